// Round 11
// baseline (1873.670 us; speedup 1.0000x reference)
//
#include <hip/hip_runtime.h>

namespace {
constexpr int T_STEPS = 50;
constexpr int BATCH_N = 131072;
constexpr int HIDDEN  = 100;
}

// Pre-kernel: interleave weights into d_ws as [h][4] = {w1a, w1b, w20, w21}.
__global__ void interleave_weights(const float* __restrict__ W1,
                                   const float* __restrict__ W2,
                                   float* __restrict__ wi) {
    int h = blockIdx.x * 64 + threadIdx.x;
    if (h < HIDDEN) {
        wi[4 * h + 0] = W1[2 * h];
        wi[4 * h + 1] = W1[2 * h + 1];
        wi[4 * h + 2] = W2[h];
        wi[4 * h + 3] = W2[HIDDEN + h];
    }
}

#define REP100(X) \
  X(0) X(1) X(2) X(3) X(4) X(5) X(6) X(7) X(8) X(9) \
  X(10) X(11) X(12) X(13) X(14) X(15) X(16) X(17) X(18) X(19) \
  X(20) X(21) X(22) X(23) X(24) X(25) X(26) X(27) X(28) X(29) \
  X(30) X(31) X(32) X(33) X(34) X(35) X(36) X(37) X(38) X(39) \
  X(40) X(41) X(42) X(43) X(44) X(45) X(46) X(47) X(48) X(49) \
  X(50) X(51) X(52) X(53) X(54) X(55) X(56) X(57) X(58) X(59) \
  X(60) X(61) X(62) X(63) X(64) X(65) X(66) X(67) X(68) X(69) \
  X(70) X(71) X(72) X(73) X(74) X(75) X(76) X(77) X(78) X(79) \
  X(80) X(81) X(82) X(83) X(84) X(85) X(86) X(87) X(88) X(89) \
  X(90) X(91) X(92) X(93) X(94) X(95) X(96) X(97) X(98) X(99)

#define SNN_DECL(H) float mm##H = 0.0f;

// Bitwise-identical arithmetic to the R7 PASS:
//   cur = fmaf(x1, w1b, x0*w1a)
//   sp  = (m_old > 0.5f) ? 1 : 0            (recomputed, not carried)
//   m   = fmaf(sp, -0.5f, fmaf(0.9f, m_old, cur))
//   sc  = (m > 0.5f) ? 1 : 0
//   acc = ascending-h serial fmaf chain (exact products)
// Weights from LDS at static offsets -> ds_read_b128, uniform-address
// broadcast (conflict-free), software-pipelined by the compiler.
#define SNN_STEP(H) { \
    const float4 w = sw4[H]; \
    const float cur = fmaf(x1, w.y, x0 * w.x); \
    const float sp  = (mm##H > 0.5f) ? 1.0f : 0.0f; \
    mm##H = fmaf(sp, -0.5f, fmaf(0.9f, mm##H, cur)); \
    const float sc  = (mm##H > 0.5f) ? 1.0f : 0.0f; \
    acc0 = fmaf(sc, w.z, acc0); \
    acc1 = fmaf(sc, w.w, acc1); }

__global__
__attribute__((amdgpu_flat_work_group_size(256, 256), amdgpu_waves_per_eu(2, 2)))
void snn_touter_lds(const unsigned int* __restrict__ x_u,
                    const float* __restrict__ wi,
                    unsigned int* __restrict__ out_u)
{
#pragma clang fp contract(off)
    __shared__ float4 sw4[HIDDEN];
    const int tid = threadIdx.x;
    if (tid < HIDDEN) {
        sw4[tid] = reinterpret_cast<const float4*>(wi)[tid];
    }
    __syncthreads();

    const int b = blockIdx.x * 256 + tid;

    REP100(SNN_DECL)

    float m20 = 0.0f, m21 = 0.0f, s20 = 0.0f, s21 = 0.0f;  // layer-2 state
    const size_t mem_off = (size_t)T_STEPS * BATCH_N * 2;

    for (int t = 0; t < T_STEPS; ++t) {
        const size_t cell = ((size_t)t * BATCH_N + b) * 2;
        const float x0 = __uint_as_float(x_u[cell]);
        const float x1 = __uint_as_float(x_u[cell + 1]);

        float acc0 = 0.0f, acc1 = 0.0f;
        REP100(SNN_STEP)

        m20 = fmaf(s20, -0.5f, fmaf(0.9f, m20, acc0));
        m21 = fmaf(s21, -0.5f, fmaf(0.9f, m21, acc1));
        s20 = (m20 > 0.5f) ? 1.0f : 0.0f;
        s21 = (m21 > 0.5f) ? 1.0f : 0.0f;

        out_u[cell]               = __float_as_uint(s20);
        out_u[cell + 1]           = __float_as_uint(s21);
        out_u[mem_off + cell]     = __float_as_uint(m20);
        out_u[mem_off + cell + 1] = __float_as_uint(m21);
    }
}

extern "C" void kernel_launch(void* const* d_in, const int* in_sizes, int n_in,
                              void* d_out, int out_size, void* d_ws, size_t ws_size,
                              hipStream_t stream) {
    // Robust input mapping: x = the unique large buffer; W1 precedes W2 among
    // the rest (holds under both dict order [x,W1,W2] and sorted [W1,W2,x]).
    int big = 0;
    for (int i = 1; i < n_in; ++i) if (in_sizes[i] > in_sizes[big]) big = i;
    const void* ptrs[3] = {nullptr, nullptr, nullptr};  // x, W1, W2
    int k = 1;
    ptrs[0] = d_in[big];
    for (int i = 0; i < n_in; ++i) {
        if (i == big) continue;
        ptrs[k++] = d_in[i];
    }
    const unsigned int* x_u = (const unsigned int*)ptrs[0];
    const float* W1 = (const float*)ptrs[1];
    const float* W2 = (const float*)ptrs[2];
    float* wi = (float*)d_ws;                 // 400 floats (16B aligned)
    unsigned int* out_u = (unsigned int*)d_out;

    hipLaunchKernelGGL(interleave_weights, dim3(2), dim3(64), 0, stream,
                       W1, W2, wi);
    hipLaunchKernelGGL(snn_touter_lds, dim3(BATCH_N / 256), dim3(256), 0,
                       stream, x_u, wi, out_u);
}

// Round 12
// 166.311 us; speedup vs baseline: 11.2661x; 11.2661x over previous
//
#include <hip/hip_runtime.h>

namespace {
constexpr int T_STEPS = 50;
constexpr int BATCH_N = 131072;
constexpr int HIDDEN  = 100;
}

// R7 structure (130us PASS, zero spill) with h processed 4-at-a-time per
// t-pass so the x[t]/acc[t] AGPR moves amortize over 4 h-channels.
// Arithmetic is bitwise-identical to R7:
//   cur = fmaf(x1, w1b, x0*w1a)
//   m   = fmaf(s_prev, -0.5f, fmaf(0.9f, m, cur))
//   s   = (m > 0.5f) ? 1.0f : 0.0f          (carried per h across t)
//   acc0/acc1: strictly h-ascending serial fmaf chain per t
// h-group loop is FORCED ROLLED (#pragma unroll 1) so only 16 weight floats
// are live at once (R11 lesson: full unroll hoists all LDS weight loads ->
// register explosion -> scratch spill).
__global__ __launch_bounds__(256)
void snn_fused_g4(const unsigned int* __restrict__ x_u,
                  const float* __restrict__ W1,
                  const float* __restrict__ W2,
                  unsigned int* __restrict__ out_u)
{
#pragma clang fp contract(off)
    __shared__ float sW1a[HIDDEN], sW1b[HIDDEN], sW20[HIDDEN], sW21[HIDDEN];

    const int tid = threadIdx.x;
    for (int i = tid; i < HIDDEN; i += 256) {
        sW1a[i] = W1[2 * i];          // W1[h][0]
        sW1b[i] = W1[2 * i + 1];      // W1[h][1]
        sW20[i] = W2[i];              // W2[0][h]
        sW21[i] = W2[HIDDEN + i];     // W2[1][h]
    }
    __syncthreads();

    const int b = blockIdx.x * 256 + tid;

    // Stage x in static-indexed arrays (AGPR-resident, proven in R7).
    float x0[T_STEPS], x1[T_STEPS];
#pragma unroll
    for (int t = 0; t < T_STEPS; ++t) {
        const size_t cell = ((size_t)t * BATCH_N + b) * 2;
        x0[t] = __uint_as_float(x_u[cell]);
        x1[t] = __uint_as_float(x_u[cell + 1]);
    }

    float acc0[T_STEPS], acc1[T_STEPS];
#pragma unroll
    for (int t = 0; t < T_STEPS; ++t) { acc0[t] = 0.0f; acc1[t] = 0.0f; }

#pragma unroll 1
    for (int h = 0; h < HIDDEN; h += 4) {
        const float waA = sW1a[h + 0], wbA = sW1b[h + 0];
        const float wcA = sW20[h + 0], wdA = sW21[h + 0];
        const float waB = sW1a[h + 1], wbB = sW1b[h + 1];
        const float wcB = sW20[h + 1], wdB = sW21[h + 1];
        const float waC = sW1a[h + 2], wbC = sW1b[h + 2];
        const float wcC = sW20[h + 2], wdC = sW21[h + 2];
        const float waD = sW1a[h + 3], wbD = sW1b[h + 3];
        const float wcD = sW20[h + 3], wdD = sW21[h + 3];

        float mA = 0.0f, sA = 0.0f, mB = 0.0f, sB = 0.0f;
        float mC = 0.0f, sC = 0.0f, mD = 0.0f, sD = 0.0f;

#pragma unroll
        for (int t = 0; t < T_STEPS; ++t) {
            const float u = x0[t];      // one AGPR read, used by 4 h's
            const float v = x1[t];

            const float curA = fmaf(v, wbA, u * waA);
            mA = fmaf(sA, -0.5f, fmaf(0.9f, mA, curA));
            sA = (mA > 0.5f) ? 1.0f : 0.0f;

            const float curB = fmaf(v, wbB, u * waB);
            mB = fmaf(sB, -0.5f, fmaf(0.9f, mB, curB));
            sB = (mB > 0.5f) ? 1.0f : 0.0f;

            const float curC = fmaf(v, wbC, u * waC);
            mC = fmaf(sC, -0.5f, fmaf(0.9f, mC, curC));
            sC = (mC > 0.5f) ? 1.0f : 0.0f;

            const float curD = fmaf(v, wbD, u * waD);
            mD = fmaf(sD, -0.5f, fmaf(0.9f, mD, curD));
            sD = (mD > 0.5f) ? 1.0f : 0.0f;

            // Strictly h-ascending serial chains (bitwise == R7).
            float a0 = acc0[t];
            a0 = fmaf(sA, wcA, a0);
            a0 = fmaf(sB, wcB, a0);
            a0 = fmaf(sC, wcC, a0);
            a0 = fmaf(sD, wcD, a0);
            acc0[t] = a0;

            float a1 = acc1[t];
            a1 = fmaf(sA, wdA, a1);
            a1 = fmaf(sB, wdB, a1);
            a1 = fmaf(sC, wdC, a1);
            a1 = fmaf(sD, wdD, a1);
            acc1[t] = a1;
        }
    }

    // Layer 2 recurrence + outputs (R7 verbatim): spk_rec then mem_rec.
    const size_t mem_off = (size_t)T_STEPS * BATCH_N * 2;
    float M0 = 0.0f, M1 = 0.0f, S0 = 0.0f, S1 = 0.0f;
#pragma unroll
    for (int t = 0; t < T_STEPS; ++t) {
        M0 = fmaf(S0, -0.5f, fmaf(0.9f, M0, acc0[t]));
        M1 = fmaf(S1, -0.5f, fmaf(0.9f, M1, acc1[t]));
        S0 = (M0 > 0.5f) ? 1.0f : 0.0f;
        S1 = (M1 > 0.5f) ? 1.0f : 0.0f;
        const size_t cell = ((size_t)t * BATCH_N + b) * 2;
        out_u[cell]               = __float_as_uint(S0);
        out_u[cell + 1]           = __float_as_uint(S1);
        out_u[mem_off + cell]     = __float_as_uint(M0);
        out_u[mem_off + cell + 1] = __float_as_uint(M1);
    }
}

extern "C" void kernel_launch(void* const* d_in, const int* in_sizes, int n_in,
                              void* d_out, int out_size, void* d_ws, size_t ws_size,
                              hipStream_t stream) {
    // Robust input mapping: x = the unique large buffer; W1 precedes W2 among
    // the rest (holds under both dict order [x,W1,W2] and sorted [W1,W2,x]).
    int big = 0;
    for (int i = 1; i < n_in; ++i) if (in_sizes[i] > in_sizes[big]) big = i;
    const void* ptrs[3] = {nullptr, nullptr, nullptr};  // x, W1, W2
    int k = 1;
    ptrs[0] = d_in[big];
    for (int i = 0; i < n_in; ++i) {
        if (i == big) continue;
        ptrs[k++] = d_in[i];
    }
    const unsigned int* x_u = (const unsigned int*)ptrs[0];
    const float* W1 = (const float*)ptrs[1];
    const float* W2 = (const float*)ptrs[2];
    unsigned int* out_u = (unsigned int*)d_out;
    hipLaunchKernelGGL(snn_fused_g4, dim3(BATCH_N / 256), dim3(256), 0,
                       stream, x_u, W1, W2, out_u);
}

// Round 13
// 149.227 us; speedup vs baseline: 12.5558x; 1.1145x over previous
//
#include <hip/hip_runtime.h>

namespace {
constexpr int T_STEPS = 50;
constexpr int BATCH_N = 131072;
constexpr int HIDDEN  = 100;
}

typedef float v2f __attribute__((ext_vector_type(2)));

// R12 g4 structure + VOP3P packed-f32 math (v_pk_fma_f32 via
// __builtin_elementwise_fma on float2). Bitwise identity: each packed
// component executes the exact R7 op sequence in the exact h-ascending order:
//   cur = fmaf(x1, w1b, x0*w1a)
//   m   = fmaf(0.9, m, cur);  m = fmaf(s_prev, -0.5, m)
//   s   = (m > 0.5) ? 1 : 0
//   acc0/acc1 (packed lanes .x/.y) += s*w, serial in h
// h-group loop FORCED ROLLED (R11 lesson: unroll hoists weight loads ->
// register explosion -> scratch spill).
__global__ __launch_bounds__(256)
void snn_fused_pk(const unsigned int* __restrict__ x_u,
                  const float* __restrict__ W1,
                  const float* __restrict__ W2,
                  unsigned int* __restrict__ out_u)
{
#pragma clang fp contract(off)
    __shared__ float sW1a[HIDDEN], sW1b[HIDDEN], sW20[HIDDEN], sW21[HIDDEN];

    const int tid = threadIdx.x;
    for (int i = tid; i < HIDDEN; i += 256) {
        sW1a[i] = W1[2 * i];          // W1[h][0]
        sW1b[i] = W1[2 * i + 1];      // W1[h][1]
        sW20[i] = W2[i];              // W2[0][h]
        sW21[i] = W2[HIDDEN + i];     // W2[1][h]
    }
    __syncthreads();

    const int b = blockIdx.x * 256 + tid;

    // Stage x (AGPR-resident static arrays, proven R7/R12).
    float x0[T_STEPS], x1[T_STEPS];
#pragma unroll
    for (int t = 0; t < T_STEPS; ++t) {
        const size_t cell = ((size_t)t * BATCH_N + b) * 2;
        x0[t] = __uint_as_float(x_u[cell]);
        x1[t] = __uint_as_float(x_u[cell + 1]);
    }

    // acc packed: .x = acc0 (out neuron 0), .y = acc1 (out neuron 1).
    v2f acc[T_STEPS];
#pragma unroll
    for (int t = 0; t < T_STEPS; ++t) acc[t] = (v2f){0.0f, 0.0f};

    const v2f K09 = {0.9f, 0.9f};
    const v2f KM5 = {-0.5f, -0.5f};

#pragma unroll 1
    for (int h = 0; h < HIDDEN; h += 4) {
        // Channel-paired layer-1 weights: {chanA, chanB} etc.
        const v2f waAB = {sW1a[h + 0], sW1a[h + 1]};
        const v2f wbAB = {sW1b[h + 0], sW1b[h + 1]};
        const v2f waCD = {sW1a[h + 2], sW1a[h + 3]};
        const v2f wbCD = {sW1b[h + 2], sW1b[h + 3]};
        // Output-paired layer-2 weights per channel: {w20[h], w21[h]}.
        const v2f wA = {sW20[h + 0], sW21[h + 0]};
        const v2f wB = {sW20[h + 1], sW21[h + 1]};
        const v2f wC = {sW20[h + 2], sW21[h + 2]};
        const v2f wD = {sW20[h + 3], sW21[h + 3]};

        v2f mAB = {0.0f, 0.0f}, mCD = {0.0f, 0.0f};
        v2f sAB = {0.0f, 0.0f}, sCD = {0.0f, 0.0f};

#pragma unroll
        for (int t = 0; t < T_STEPS; ++t) {
            const float u = x0[t];
            const float v = x1[t];
            const v2f uu = {u, u};
            const v2f vv = {v, v};

            v2f curAB = __builtin_elementwise_fma(vv, wbAB, uu * waAB);
            v2f curCD = __builtin_elementwise_fma(vv, wbCD, uu * waCD);

            mAB = __builtin_elementwise_fma(K09, mAB, curAB);
            mAB = __builtin_elementwise_fma(sAB, KM5, mAB);
            sAB.x = (mAB.x > 0.5f) ? 1.0f : 0.0f;
            sAB.y = (mAB.y > 0.5f) ? 1.0f : 0.0f;

            mCD = __builtin_elementwise_fma(K09, mCD, curCD);
            mCD = __builtin_elementwise_fma(sCD, KM5, mCD);
            sCD.x = (mCD.x > 0.5f) ? 1.0f : 0.0f;
            sCD.y = (mCD.y > 0.5f) ? 1.0f : 0.0f;

            // Strictly h-ascending serial chain (per component == R7).
            v2f a = acc[t];
            a = __builtin_elementwise_fma((v2f){sAB.x, sAB.x}, wA, a);
            a = __builtin_elementwise_fma((v2f){sAB.y, sAB.y}, wB, a);
            a = __builtin_elementwise_fma((v2f){sCD.x, sCD.x}, wC, a);
            a = __builtin_elementwise_fma((v2f){sCD.y, sCD.y}, wD, a);
            acc[t] = a;
        }
    }

    // Layer 2 recurrence (packed) + outputs: spk_rec then mem_rec.
    const size_t mem_off = (size_t)T_STEPS * BATCH_N * 2;
    v2f M = {0.0f, 0.0f};
    v2f S = {0.0f, 0.0f};
#pragma unroll
    for (int t = 0; t < T_STEPS; ++t) {
        M = __builtin_elementwise_fma(K09, M, acc[t]);
        M = __builtin_elementwise_fma(S, KM5, M);
        S.x = (M.x > 0.5f) ? 1.0f : 0.0f;
        S.y = (M.y > 0.5f) ? 1.0f : 0.0f;
        const size_t cell = ((size_t)t * BATCH_N + b) * 2;
        out_u[cell]               = __float_as_uint(S.x);
        out_u[cell + 1]           = __float_as_uint(S.y);
        out_u[mem_off + cell]     = __float_as_uint(M.x);
        out_u[mem_off + cell + 1] = __float_as_uint(M.y);
    }
}

extern "C" void kernel_launch(void* const* d_in, const int* in_sizes, int n_in,
                              void* d_out, int out_size, void* d_ws, size_t ws_size,
                              hipStream_t stream) {
    // Robust input mapping: x = the unique large buffer; W1 precedes W2 among
    // the rest (holds under both dict order [x,W1,W2] and sorted [W1,W2,x]).
    int big = 0;
    for (int i = 1; i < n_in; ++i) if (in_sizes[i] > in_sizes[big]) big = i;
    const void* ptrs[3] = {nullptr, nullptr, nullptr};  // x, W1, W2
    int k = 1;
    ptrs[0] = d_in[big];
    for (int i = 0; i < n_in; ++i) {
        if (i == big) continue;
        ptrs[k++] = d_in[i];
    }
    const unsigned int* x_u = (const unsigned int*)ptrs[0];
    const float* W1 = (const float*)ptrs[1];
    const float* W2 = (const float*)ptrs[2];
    unsigned int* out_u = (unsigned int*)d_out;
    hipLaunchKernelGGL(snn_fused_pk, dim3(BATCH_N / 256), dim3(256), 0,
                       stream, x_u, W1, W2, out_u);
}